// Round 3
// baseline (437.385 us; speedup 1.0000x reference)
//
#include <hip/hip_runtime.h>
#include <hip/hip_bf16.h>

typedef __attribute__((ext_vector_type(4))) float f32x4;
typedef __attribute__((ext_vector_type(8))) short short8;

#define HH 512
#define BB 32
#define SS 2048
#define KK 1024  // 2H

__device__ __forceinline__ unsigned short f2bf(float f) {
    unsigned int u = __float_as_uint(f);
    u += 0x7fffu + ((u >> 16) & 1u);
    return (unsigned short)(u >> 16);
}

__device__ __forceinline__ float fast_tanh(float x) {
    float e = __expf(2.0f * x);
    return 1.0f - 2.0f / (e + 1.0f);
}

// ---------------- kernel 1: spb[b][h] = output[b]·W_s[h] + b_attn[h] ----------------
__global__ __launch_bounds__(256)
void spb_kernel(const float* __restrict__ out_state,
                const float* __restrict__ W,
                const float* __restrict__ bias,
                float* __restrict__ spb) {
    int wave = threadIdx.x >> 6, lane = threadIdx.x & 63;
    int g = blockIdx.x * 4 + wave;       // 16384 (b,h) pairs
    int b = g >> 9, h = g & 511;
    const float* wr = W + (size_t)h * 1536;      // W_s row h
    const float* ov = out_state + b * HH;
    float4 w0 = *(const float4*)(wr + lane * 8);
    float4 w1 = *(const float4*)(wr + lane * 8 + 4);
    float4 o0 = *(const float4*)(ov + lane * 8);
    float4 o1 = *(const float4*)(ov + lane * 8 + 4);
    float d = w0.x * o0.x + w0.y * o0.y + w0.z * o0.z + w0.w * o0.w
            + w1.x * o1.x + w1.y * o1.y + w1.z * o1.z + w1.w * o1.w;
    d += __shfl_xor(d, 1); d += __shfl_xor(d, 2); d += __shfl_xor(d, 4);
    d += __shfl_xor(d, 8); d += __shfl_xor(d, 16); d += __shfl_xor(d, 32);
    if (lane == 0) spb[g] = d + bias[h];
}

// ------- kernel 2: W_e -> bf16, FRAG-MAJOR layout Wt[kt][g][lane][8] -------
// g = h>>4 (16-row group), lane = (q<<4)|(h&15) with q = (k>>3)&3, j = k&7.
// A wave's B-frag load in the GEMM is then 64 lanes x 16B CONTIGUOUS (16 lines).
__global__ void wconv_kernel(const float* __restrict__ W, unsigned short* __restrict__ Wt) {
    int idx = blockIdx.x * 256 + threadIdx.x;   // 65536 threads, 8 elems each
    int e8 = idx * 8;
    int h = e8 >> 10;        // [0,512)
    int k = e8 & 1023;       // multiple of 8
    const float* src = W + (size_t)h * 1536 + 512 + k;
    float4 w0 = *(const float4*)src;
    float4 w1 = *(const float4*)(src + 4);
    int kt = k >> 5;
    int q  = (k >> 3) & 3;
    int g  = h >> 4;
    int r  = h & 15;
    int ln = (q << 4) | r;
    unsigned short* dst = Wt + (size_t)kt * 16384 + g * 512 + ln * 8;
    ushort4 p0, p1;
    p0.x = f2bf(w0.x); p0.y = f2bf(w0.y); p0.z = f2bf(w0.z); p0.w = f2bf(w0.w);
    p1.x = f2bf(w1.x); p1.y = f2bf(w1.y); p1.z = f2bf(w1.z); p1.w = f2bf(w1.w);
    *(ushort4*)dst = p0;
    *(ushort4*)(dst + 4) = p1;
}

// ---------------- kernel 3: fused GEMM + tanh + v-dot -> scores[b][s] ----------------
// 512 thr (8 waves). Block tile M=64 (one b, 64 s) x N=512 (full H); wave w: cols
// [w*64, w*64+64), acc 4x4 frags = 64 regs. A: dbuf LDS, one barrier/iter.
// B: read straight from L2-resident frag-major Wt — coalesced 1KB per instruction.
__global__ __launch_bounds__(512, 4)
void attn_gemm(const float* __restrict__ enc, const unsigned short* __restrict__ Wt,
               const float* __restrict__ spb, const float* __restrict__ vvec,
               float* __restrict__ scores) {
    __shared__ unsigned short Asm[2 * 64 * 32];  // 8 KB double-buffered
    __shared__ float red[8][64];

    const int tid = threadIdx.x;
    const int w = tid >> 6;
    const int lane = tid & 63;
    const int r = lane & 15;
    const int q = lane >> 4;
    const int b = blockIdx.x >> 5;
    const int s0 = (blockIdx.x & 31) << 6;

    // A staging: thread -> row=tid>>3, 4 floats at k-offset (tid&7)*4
    const int arow = tid >> 3;
    const int akq = tid & 7;
    const float4* aptr = (const float4*)(enc + ((size_t)(b * SS + s0 + arow)) * KK + akq * 4);
    const int st_off = arow * 32 + akq * 4;          // ushort units
    const int rd_off = r * 32 + q * 8;               // frag read base
    // frag-major B base: g = w*4+nf -> byte offset (w*2048 + nf*512 + lane*8) ushorts
    const unsigned short* wbase = Wt + (size_t)w * 2048 + lane * 8;

    f32x4 acc[4][4] = {};

    // preload tile 0
    float4 f = aptr[0]; aptr += 8;
    {
        ushort4 p;
        p.x = f2bf(f.x); p.y = f2bf(f.y); p.z = f2bf(f.z); p.w = f2bf(f.w);
        *(ushort4*)(Asm + st_off) = p;
    }
    __syncthreads();

    for (int kt = 0; kt < 31; ++kt) {
        float4 fn = aptr[0]; aptr += 8;  // next A tile (HBM)

        const short8* wp = (const short8*)(wbase + (size_t)kt * 16384);
        short8 bf[4];
        #pragma unroll
        for (int nf = 0; nf < 4; ++nf) bf[nf] = wp[nf * 64];   // contiguous 1KB frags

        const short8* ap = (const short8*)(Asm + (kt & 1) * 2048 + rd_off);
        short8 af[4];
        #pragma unroll
        for (int mt = 0; mt < 4; ++mt) af[mt] = ap[mt * 64];

        #pragma unroll
        for (int mt = 0; mt < 4; ++mt)
            #pragma unroll
            for (int nf = 0; nf < 4; ++nf)
                acc[mt][nf] = __builtin_amdgcn_mfma_f32_16x16x32_bf16(
                    af[mt], bf[nf], acc[mt][nf], 0, 0, 0);

        ushort4 p;
        p.x = f2bf(fn.x); p.y = f2bf(fn.y); p.z = f2bf(fn.z); p.w = f2bf(fn.w);
        *(ushort4*)(Asm + ((kt + 1) & 1) * 2048 + st_off) = p;
        __syncthreads();
    }
    // last tile (kt=31)
    {
        const short8* wp = (const short8*)(wbase + (size_t)31 * 16384);
        short8 bf[4];
        #pragma unroll
        for (int nf = 0; nf < 4; ++nf) bf[nf] = wp[nf * 64];
        const short8* ap = (const short8*)(Asm + (31 & 1) * 2048 + rd_off);
        short8 af[4];
        #pragma unroll
        for (int mt = 0; mt < 4; ++mt) af[mt] = ap[mt * 64];
        #pragma unroll
        for (int mt = 0; mt < 4; ++mt)
            #pragma unroll
            for (int nf = 0; nf < 4; ++nf)
                acc[mt][nf] = __builtin_amdgcn_mfma_f32_16x16x32_bf16(
                    af[mt], bf[nf], acc[mt][nf], 0, 0, 0);
    }

    // ---- epilogue: partial score = sum over this wave's 64 cols of v[h]*tanh(.+spb)
    float vh[4], sh[4];
    #pragma unroll
    for (int nf = 0; nf < 4; ++nf) {
        int h = w * 64 + nf * 16 + r;
        vh[nf] = vvec[h];
        sh[nf] = spb[b * HH + h];
    }
    float rowacc[4][4] = {};
    #pragma unroll
    for (int mt = 0; mt < 4; ++mt)
        #pragma unroll
        for (int nf = 0; nf < 4; ++nf)
            #pragma unroll
            for (int i = 0; i < 4; ++i) {
                float x = acc[mt][nf][i] + sh[nf];
                rowacc[mt][i] += vh[nf] * fast_tanh(x);
            }
    #pragma unroll
    for (int mt = 0; mt < 4; ++mt)
        #pragma unroll
        for (int i = 0; i < 4; ++i) {
            float t = rowacc[mt][i];
            t += __shfl_xor(t, 1);
            t += __shfl_xor(t, 2);
            t += __shfl_xor(t, 4);
            t += __shfl_xor(t, 8);
            rowacc[mt][i] = t;
        }
    if (r == 0) {
        #pragma unroll
        for (int mt = 0; mt < 4; ++mt)
            #pragma unroll
            for (int i = 0; i < 4; ++i)
                red[w][mt * 16 + q * 4 + i] = rowacc[mt][i];  // row = mt*16+q*4+i
    }
    __syncthreads();
    if (tid < 64) {
        float sum = 0.f;
        #pragma unroll
        for (int ww = 0; ww < 8; ++ww) sum += red[ww][tid];
        scores[b * SS + s0 + tid] = sum;
    }
}

// ---------------- kernel 4: masked softmax over S per batch ----------------
__global__ void softmax_kernel(const float* __restrict__ scores,
                               const int* __restrict__ mask,
                               float* __restrict__ out) {
    __shared__ float red[256];
    int b = blockIdx.x, tid = threadIdx.x;
    float x[8];
    #pragma unroll
    for (int i = 0; i < 8; ++i) {
        int s = tid + i * 256;
        float sc = scores[b * SS + s];
        if (mask[b * SS + s] == 0) sc -= 1000.0f;
        x[i] = sc;
    }
    float mx = x[0];
    #pragma unroll
    for (int i = 1; i < 8; ++i) mx = fmaxf(mx, x[i]);
    red[tid] = mx;
    __syncthreads();
    for (int o = 128; o > 0; o >>= 1) {
        if (tid < o) red[tid] = fmaxf(red[tid], red[tid + o]);
        __syncthreads();
    }
    mx = red[0];
    __syncthreads();
    float e[8], sum = 0.f;
    #pragma unroll
    for (int i = 0; i < 8; ++i) { e[i] = __expf(x[i] - mx); sum += e[i]; }
    red[tid] = sum;
    __syncthreads();
    for (int o = 128; o > 0; o >>= 1) {
        if (tid < o) red[tid] += red[tid + o];
        __syncthreads();
    }
    float inv = 1.0f / red[0];
    #pragma unroll
    for (int i = 0; i < 8; ++i) out[b * SS + tid + i * 256] = e[i] * inv;
}

extern "C" void kernel_launch(void* const* d_in, const int* in_sizes, int n_in,
                              void* d_out, int out_size, void* d_ws, size_t ws_size,
                              hipStream_t stream) {
    const float* out_state = (const float*)d_in[0];   // (32, 512)
    const float* enc       = (const float*)d_in[1];   // (32, 2048, 1024)
    const int*   mask      = (const int*)d_in[2];     // (32, 2048)
    const float* W_attn    = (const float*)d_in[3];   // (512, 1536)
    const float* b_attn    = (const float*)d_in[4];   // (512,)
    const float* vvec      = (const float*)d_in[5];   // (512,)
    float* out = (float*)d_out;                       // (32, 1, 2048)

    char* ws = (char*)d_ws;
    float*          spb    = (float*)ws;                         // 64 KB
    unsigned short* Wt     = (unsigned short*)(ws + 65536);      // 1 MB
    float*          scores = (float*)(ws + 65536 + 1048576);     // 256 KB

    spb_kernel<<<4096, 256, 0, stream>>>(out_state, W_attn, b_attn, spb);
    wconv_kernel<<<256, 256, 0, stream>>>(W_attn, Wt);
    attn_gemm<<<1024, 512, 0, stream>>>(enc, Wt, spb, vvec, scores);
    softmax_kernel<<<32, 256, 0, stream>>>(scores, mask, out);
}

// Round 4
// 429.134 us; speedup vs baseline: 1.0192x; 1.0192x over previous
//
#include <hip/hip_runtime.h>
#include <hip/hip_bf16.h>

typedef __attribute__((ext_vector_type(4))) float f32x4;
typedef __attribute__((ext_vector_type(8))) short short8;

#define HH 512
#define BB 32
#define SS 2048
#define KK 1024  // 2H

__device__ __forceinline__ unsigned short f2bf(float f) {
    unsigned int u = __float_as_uint(f);
    u += 0x7fffu + ((u >> 16) & 1u);
    return (unsigned short)(u >> 16);
}

__device__ __forceinline__ ushort4 pack4(float4 f) {
    ushort4 p;
    p.x = f2bf(f.x); p.y = f2bf(f.y); p.z = f2bf(f.z); p.w = f2bf(f.w);
    return p;
}

__device__ __forceinline__ float fast_tanh(float x) {
    float e = __expf(2.0f * x);
    return 1.0f - 2.0f / (e + 1.0f);
}

// ---------------- kernel 1: spb[b][h] = output[b]·W_s[h] + b_attn[h] ----------------
__global__ __launch_bounds__(256)
void spb_kernel(const float* __restrict__ out_state,
                const float* __restrict__ W,
                const float* __restrict__ bias,
                float* __restrict__ spb) {
    int wave = threadIdx.x >> 6, lane = threadIdx.x & 63;
    int g = blockIdx.x * 4 + wave;       // 16384 (b,h) pairs
    int b = g >> 9, h = g & 511;
    const float* wr = W + (size_t)h * 1536;      // W_s row h
    const float* ov = out_state + b * HH;
    float4 w0 = *(const float4*)(wr + lane * 8);
    float4 w1 = *(const float4*)(wr + lane * 8 + 4);
    float4 o0 = *(const float4*)(ov + lane * 8);
    float4 o1 = *(const float4*)(ov + lane * 8 + 4);
    float d = w0.x * o0.x + w0.y * o0.y + w0.z * o0.z + w0.w * o0.w
            + w1.x * o1.x + w1.y * o1.y + w1.z * o1.z + w1.w * o1.w;
    d += __shfl_xor(d, 1); d += __shfl_xor(d, 2); d += __shfl_xor(d, 4);
    d += __shfl_xor(d, 8); d += __shfl_xor(d, 16); d += __shfl_xor(d, 32);
    if (lane == 0) spb[g] = d + bias[h];
}

// ------- kernel 2: W_e -> bf16, FRAG-MAJOR layout Wt[kt][g][lane][8] -------
// g = h>>4, lane = (q<<4)|(h&15), q = (k>>3)&3: a wave's B-frag load in the
// GEMM is 64 lanes x 16B contiguous.
__global__ void wconv_kernel(const float* __restrict__ W, unsigned short* __restrict__ Wt) {
    int idx = blockIdx.x * 256 + threadIdx.x;   // 65536 threads, 8 elems each
    int e8 = idx * 8;
    int h = e8 >> 10;        // [0,512)
    int k = e8 & 1023;       // multiple of 8
    const float* src = W + (size_t)h * 1536 + 512 + k;
    float4 w0 = *(const float4*)src;
    float4 w1 = *(const float4*)(src + 4);
    int kt = k >> 5;
    int q  = (k >> 3) & 3;
    int g  = h >> 4;
    int r  = h & 15;
    int ln = (q << 4) | r;
    unsigned short* dst = Wt + (size_t)kt * 16384 + g * 512 + ln * 8;
    *(ushort4*)dst = pack4(w0);
    *(ushort4*)(dst + 4) = pack4(w1);
}

// ---------------- kernel 3: fused GEMM + tanh + v-dot -> scores[b][s] ----------------
// 512 thr (8 waves). Block tile M=64 x N=512; wave w: cols [w*64,w*64+64),
// acc 4x4 frags (64 AGPRs). BK=128: 4 K-tiles staged per barrier period
// (64B/thread in flight, dbuf 2x16KB LDS, 9 barriers total vs 33).
// B frags straight from L2-resident frag-major Wt.
__global__ __launch_bounds__(512, 4)
void attn_gemm(const float* __restrict__ enc, const unsigned short* __restrict__ Wt,
               const float* __restrict__ spb, const float* __restrict__ vvec,
               float* __restrict__ scores) {
    __shared__ unsigned short Asm[2 * 8192];  // 2 bufs x 4 tiles x (64x32) = 32 KB
    __shared__ float red[8][64];

    const int tid = threadIdx.x;
    const int w = tid >> 6;
    const int lane = tid & 63;
    const int r = lane & 15;
    const int q = lane >> 4;
    const int b = blockIdx.x >> 5;
    const int s0 = (blockIdx.x & 31) << 6;

    // A staging: thread -> row=tid>>3, 4 floats at k-offset (tid&7)*4 within a tile
    const int arow = tid >> 3;
    const int akq = tid & 7;
    const float* arowp = enc + ((size_t)(b * SS + s0 + arow)) * KK + akq * 4;
    const int st_off = tid * 4;              // ushort units within a 2048-ushort tile
    const int rd_off = r * 32 + q * 8;       // frag read base within a tile
    const unsigned short* wbase = Wt + (size_t)w * 2048 + lane * 8;  // frag-major B

    f32x4 acc[4][4] = {};
    float4 f[4];

    // preamble: stage period 0 into buf 0
    #pragma unroll
    for (int t = 0; t < 4; ++t) f[t] = *(const float4*)(arowp + t * 32);
    #pragma unroll
    for (int t = 0; t < 4; ++t)
        *(ushort4*)(Asm + t * 2048 + st_off) = pack4(f[t]);
    __syncthreads();

    for (int p = 0; p < 8; ++p) {
        const int buf = p & 1;
        if (p < 7) {   // issue next period's 4 A-loads immediately after barrier
            const float* src = arowp + (p + 1) * 128;
            #pragma unroll
            for (int t = 0; t < 4; ++t) f[t] = *(const float4*)(src + t * 32);
        }
        #pragma unroll
        for (int sub = 0; sub < 4; ++sub) {
            const int kt = p * 4 + sub;
            const short8* wp = (const short8*)(wbase + (size_t)kt * 16384);
            short8 bf[4];
            #pragma unroll
            for (int nf = 0; nf < 4; ++nf) bf[nf] = wp[nf * 64];
            const short8* ap = (const short8*)(Asm + buf * 8192 + sub * 2048 + rd_off);
            short8 af[4];
            #pragma unroll
            for (int mt = 0; mt < 4; ++mt) af[mt] = ap[mt * 64];
            #pragma unroll
            for (int mt = 0; mt < 4; ++mt)
                #pragma unroll
                for (int nf = 0; nf < 4; ++nf)
                    acc[mt][nf] = __builtin_amdgcn_mfma_f32_16x16x32_bf16(
                        af[mt], bf[nf], acc[mt][nf], 0, 0, 0);
        }
        if (p < 7) {
            unsigned short* dst = Asm + (buf ^ 1) * 8192 + st_off;
            #pragma unroll
            for (int t = 0; t < 4; ++t)
                *(ushort4*)(dst + t * 2048) = pack4(f[t]);
            __syncthreads();
        }
    }

    // ---- epilogue: partial score = sum over this wave's 64 cols of v[h]*tanh(.+spb)
    float vh[4], sh[4];
    #pragma unroll
    for (int nf = 0; nf < 4; ++nf) {
        int h = w * 64 + nf * 16 + r;
        vh[nf] = vvec[h];
        sh[nf] = spb[b * HH + h];
    }
    float rowacc[4][4] = {};
    #pragma unroll
    for (int mt = 0; mt < 4; ++mt)
        #pragma unroll
        for (int nf = 0; nf < 4; ++nf)
            #pragma unroll
            for (int i = 0; i < 4; ++i) {
                float x = acc[mt][nf][i] + sh[nf];
                rowacc[mt][i] += vh[nf] * fast_tanh(x);
            }
    #pragma unroll
    for (int mt = 0; mt < 4; ++mt)
        #pragma unroll
        for (int i = 0; i < 4; ++i) {
            float t = rowacc[mt][i];
            t += __shfl_xor(t, 1);
            t += __shfl_xor(t, 2);
            t += __shfl_xor(t, 4);
            t += __shfl_xor(t, 8);
            rowacc[mt][i] = t;
        }
    if (r == 0) {
        #pragma unroll
        for (int mt = 0; mt < 4; ++mt)
            #pragma unroll
            for (int i = 0; i < 4; ++i)
                red[w][mt * 16 + q * 4 + i] = rowacc[mt][i];  // row = mt*16+q*4+i
    }
    __syncthreads();
    if (tid < 64) {
        float sum = 0.f;
        #pragma unroll
        for (int ww = 0; ww < 8; ++ww) sum += red[ww][tid];
        scores[b * SS + s0 + tid] = sum;
    }
}

// ---------------- kernel 4: masked softmax over S per batch ----------------
__global__ void softmax_kernel(const float* __restrict__ scores,
                               const int* __restrict__ mask,
                               float* __restrict__ out) {
    __shared__ float red[256];
    int b = blockIdx.x, tid = threadIdx.x;
    float x[8];
    #pragma unroll
    for (int i = 0; i < 8; ++i) {
        int s = tid + i * 256;
        float sc = scores[b * SS + s];
        if (mask[b * SS + s] == 0) sc -= 1000.0f;
        x[i] = sc;
    }
    float mx = x[0];
    #pragma unroll
    for (int i = 1; i < 8; ++i) mx = fmaxf(mx, x[i]);
    red[tid] = mx;
    __syncthreads();
    for (int o = 128; o > 0; o >>= 1) {
        if (tid < o) red[tid] = fmaxf(red[tid], red[tid + o]);
        __syncthreads();
    }
    mx = red[0];
    __syncthreads();
    float e[8], sum = 0.f;
    #pragma unroll
    for (int i = 0; i < 8; ++i) { e[i] = __expf(x[i] - mx); sum += e[i]; }
    red[tid] = sum;
    __syncthreads();
    for (int o = 128; o > 0; o >>= 1) {
        if (tid < o) red[tid] += red[tid + o];
        __syncthreads();
    }
    float inv = 1.0f / red[0];
    #pragma unroll
    for (int i = 0; i < 8; ++i) out[b * SS + tid + i * 256] = e[i] * inv;
}

extern "C" void kernel_launch(void* const* d_in, const int* in_sizes, int n_in,
                              void* d_out, int out_size, void* d_ws, size_t ws_size,
                              hipStream_t stream) {
    const float* out_state = (const float*)d_in[0];   // (32, 512)
    const float* enc       = (const float*)d_in[1];   // (32, 2048, 1024)
    const int*   mask      = (const int*)d_in[2];     // (32, 2048)
    const float* W_attn    = (const float*)d_in[3];   // (512, 1536)
    const float* b_attn    = (const float*)d_in[4];   // (512,)
    const float* vvec      = (const float*)d_in[5];   // (512,)
    float* out = (float*)d_out;                       // (32, 1, 2048)

    char* ws = (char*)d_ws;
    float*          spb    = (float*)ws;                         // 64 KB
    unsigned short* Wt     = (unsigned short*)(ws + 65536);      // 1 MB
    float*          scores = (float*)(ws + 65536 + 1048576);     // 256 KB

    spb_kernel<<<4096, 256, 0, stream>>>(out_state, W_attn, b_attn, spb);
    wconv_kernel<<<256, 256, 0, stream>>>(W_attn, Wt);
    attn_gemm<<<1024, 512, 0, stream>>>(enc, Wt, spb, vvec, scores);
    softmax_kernel<<<32, 256, 0, stream>>>(scores, mask, out);
}